// Round 16
// baseline (626.778 us; speedup 1.0000x reference)
//
#include <hip/hip_runtime.h>

// GRU reward model, round 16: TWO INDEPENDENT SEQ-STREAMS per block.
//   B=1024 seqs, T=1024 steps, Din=36 (obs32+act4+bias), H=64, gates 3H=192.
//   32 blocks x 512 threads (8 waves = 2/SIMD); block owns 32 seqs as two
//   independent 16-seq recurrences X and Y. Set A (waves 0-3) owns EVEN steps,
//   set B (waves 4-7) ODD steps (r14 role-alternation, proven correct).
//   r15 postmortem: wall = serial h-chain with ~30% idle issue; neither extra
//   waves nor setprio filled it. This round fills it with IN-WAVE ILP: each
//   HEAVY phase runs step t for X and Y back-to-back -> two independent dep
//   chains interleave statically; Y issues inside X's latency bubbles.
//   Weights (A-fragments) are shared across streams; only gi/x/h state
//   duplicates. Math identical per stream -> absmax must be 0.0078125.

#define BB 1024
#define TT 1024
#define DOBS 32
#define DACT 4
#define HH 64

typedef __attribute__((ext_vector_type(8))) short short8;
typedef __attribute__((ext_vector_type(4))) float f32x4;

#define MFMA(A, B, C) __builtin_amdgcn_mfma_f32_16x16x32_bf16((A), (B), (C), 0, 0, 0)

static __device__ __forceinline__ unsigned short f2bf(float f) {
    unsigned u = __float_as_uint(f);
    u += 0x7fffu + ((u >> 16) & 1u);   // RNE
    return (unsigned short)(u >> 16);
}
static __device__ __forceinline__ float frcp(float x) { return __builtin_amdgcn_rcpf(x); }
static __device__ __forceinline__ unsigned cvt_pk(float lo, float hi) {
    unsigned r;
    asm("v_cvt_pk_bf16_f32 %0, %1, %2" : "=v"(r) : "v"(lo), "v"(hi));
    return r;
}

#define L2E 1.442695040888963f

// ---- pre-kernel: xext[(b*TT+t)*40] = bf16 [obs(32), act(4), 1.0, 0,0,0] ----
__global__ __launch_bounds__(256)
void pack_x(const float* __restrict__ obs, const float* __restrict__ act,
            unsigned short* __restrict__ xext)
{
    const size_t r = (size_t)blockIdx.x * 256 + threadIdx.x;   // (b,t) row
    const float* o = obs + r * DOBS;
    unsigned short* d = xext + r * 40;
    short8 v[5];
#pragma unroll
    for (int j = 0; j < 4; ++j) {
        float4 a = ((const float4*)o)[2 * j];
        float4 b = ((const float4*)o)[2 * j + 1];
        short8 t;
        t[0]=f2bf(a.x); t[1]=f2bf(a.y); t[2]=f2bf(a.z); t[3]=f2bf(a.w);
        t[4]=f2bf(b.x); t[5]=f2bf(b.y); t[6]=f2bf(b.z); t[7]=f2bf(b.w);
        v[j] = t;
    }
    {
        float4 a = *(const float4*)(act + r * DACT);
        short8 t;
        t[0]=f2bf(a.x); t[1]=f2bf(a.y); t[2]=f2bf(a.z); t[3]=f2bf(a.w);
        t[4]=(short)0x3f80; t[5]=0; t[6]=0; t[7]=0;   // bias slot k=36
        v[4] = t;
    }
#pragma unroll
    for (int j = 0; j < 5; ++j) ((short8*)d)[j] = v[j];
}

// LOADX: fetch x(t) B-fragments for stream base PX (seq fixed per stream).
#define LOADX(PX, XO, XA, T)                                                   \
  {                                                                            \
    XO = *(const short8*)((PX) + (size_t)(T) * 40 + 8 * q);                    \
    XA = (q == 0) ? *(const short8*)((PX) + (size_t)(T) * 40 + 32) : zero8;    \
  }

// GATES: one stream's gate+blend block (C fragments -> new hold, packed write)
#define GATES(CRF, CZF, CNHF, CNIF, HP, HOLD, HB, F32, PH)                     \
    _Pragma("unroll")                                                          \
    for (int reg = 0; reg < 4; ++reg) {                                        \
      float rr   = frcp(1.0f + __builtin_amdgcn_exp2f(CRF[reg]));              \
      float zz   = frcp(1.0f + __builtin_amdgcn_exp2f(CZF[reg]));              \
      float E    = __builtin_amdgcn_exp2f(__builtin_fmaf(rr, CNHF[reg], CNIF[reg])); \
      float nn   = __builtin_fmaf(-2.0f, frcp(E + 1.0f), 1.0f);                \
      HOLD[reg]  = __builtin_fmaf(zz, HP[reg] - nn, nn);                       \
    }                                                                          \
    *(uint2*)((char*)HB[PH ^ 1] + wraddr) =                                    \
        make_uint2(cvt_pk(HOLD[0], HOLD[1]), cvt_pk(HOLD[2], HOLD[3]));        \
    *(f32x4*)((char*)F32[PH ^ 1] + f32addr) = HOLD;

// HEAVY: h-dependent step work for BOTH streams. PH literal.
#define HEAVY(PH, T, IT)                                                       \
  {                                                                            \
    __builtin_amdgcn_s_setprio(1);                                             \
    short8 Ax0 = *(const short8*)((const char*)hbX[PH] + rdaddr0);             \
    short8 Ax1 = *(const short8*)((const char*)hbX[PH] + rdaddr1);             \
    short8 Ay0 = *(const short8*)((const char*)hbY[PH] + rdaddr0);             \
    short8 Ay1 = *(const short8*)((const char*)hbY[PH] + rdaddr1);             \
    f32x4 hpX = *(const f32x4*)((const char*)hfX[PH] + f32addr);               \
    f32x4 hpY = *(const f32x4*)((const char*)hfY[PH] + f32addr);               \
    f32x4 CrX  = MFMA(AH[0][1], Ax1, MFMA(AH[0][0], Ax0, cgrX));               \
    f32x4 CrY  = MFMA(AH[0][1], Ay1, MFMA(AH[0][0], Ay0, cgrY));               \
    f32x4 CzX  = MFMA(AH[1][1], Ax1, MFMA(AH[1][0], Ax0, cgzX));               \
    f32x4 CzY  = MFMA(AH[1][1], Ay1, MFMA(AH[1][0], Ay0, cgzY));               \
    f32x4 CnhX = MFMA(AH[2][1], Ax1, MFMA(AH[2][0], Ax0, bhn4));               \
    f32x4 CnhY = MFMA(AH[2][1], Ay1, MFMA(AH[2][0], Ay0, bhn4));               \
    f32x4 CrwX = zf, CrwY = zf;                                                \
    const bool dorw_ = (w == ((IT) & 3));                                      \
    if (dorw_) {                                                               \
      CrwX = MFMA(AR[1], Ax1, MFMA(AR[0], Ax0, zf));                           \
      CrwY = MFMA(AR[1], Ay1, MFMA(AR[0], Ay0, zf));                           \
    }                                                                          \
    GATES(CrX, CzX, CnhX, cgnX, hpX, holdX, hbX, hfX, PH)                      \
    GATES(CrY, CzY, CnhY, cgnY, hpY, holdY, hbY, hfY, PH)                      \
    if (dorw_ && q == 0 && (T) > 0) {                                          \
      rew[(size_t)(bid * 32 + c) * TT + (T) - 1]      = CrwX[0] + brr;         \
      rew[(size_t)(bid * 32 + 16 + c) * TT + (T) - 1] = CrwY[0] + brr;         \
    }                                                                          \
    asm volatile("s_waitcnt lgkmcnt(0)" ::: "memory");                         \
    __builtin_amdgcn_s_setprio(0);                                             \
  }

// LIGHT: gi(T2) for both streams from the x rings, then refill rings (T2+2).
#define LIGHT(T2)                                                              \
  {                                                                            \
    cgrX = MFMA(AX[0][1], xaX, MFMA(AX[0][0], xoX, zf));                       \
    cgrY = MFMA(AX[0][1], xaY, MFMA(AX[0][0], xoY, zf));                       \
    cgzX = MFMA(AX[1][1], xaX, MFMA(AX[1][0], xoX, zf));                       \
    cgzY = MFMA(AX[1][1], xaY, MFMA(AX[1][0], xoY, zf));                       \
    cgnX = MFMA(AX[2][1], xaX, MFMA(AX[2][0], xoX, zf));                       \
    cgnY = MFMA(AX[2][1], xaY, MFMA(AX[2][0], xoY, zf));                       \
    LOADX(pxX, xoX, xaX, (T2) + 2)                                             \
    LOADX(pxY, xoY, xaY, (T2) + 2)                                             \
  }

__global__ __launch_bounds__(512, 1)
void gru_fused(const unsigned short* __restrict__ xext,
               const float* __restrict__ W_ih, const float* __restrict__ b_ih,
               const float* __restrict__ W_hh, const float* __restrict__ b_hh,
               const float* __restrict__ W_r, const float* __restrict__ b_r,
               float* __restrict__ out)
{
    const int tid = threadIdx.x;
    const int set = tid >> 8;                // 0: even steps, 1: odd steps
    const int w = (tid >> 6) & 3;            // wave-in-set
    const int l = tid & 63, c = l & 15, q = l >> 4;
    const int bid = blockIdx.x;
    const int u0 = 16 * w + 4 * q;           // first of this lane's 4 units

    // [parity][seq][unit]; X and Y streams have separate buffers
    __shared__ __align__(16) unsigned short hbX[2][16 * 64], hbY[2][16 * 64];
    __shared__ __align__(16) float          hfX[2][16 * 64], hfY[2][16 * 64];

    // ---- weight A-fragments, PRE-SCALED (shared by both streams) ----
    //   m=0 (r), m=1 (z): rows * -L2E;  m=2 (n): rows * +2*L2E.
    short8 AX[3][2], AH[3][2];
#pragma unroll
    for (int m = 0; m < 3; ++m) {
        const float sc = (m == 2) ? (2.0f * L2E) : (-L2E);
        const int j = w + 4 * m;             // tile: w=r, w+4=z, w+8=n
        const int g = 16 * j + c;            // gate row (A-row = c)
        {   // x-weights, k 0..31
            const float* wp = W_ih + (size_t)g * 36 + 8 * q;
            float4 a = *(const float4*)wp, b = *(const float4*)(wp + 4);
            short8 f;
            f[0]=f2bf(a.x*sc); f[1]=f2bf(a.y*sc); f[2]=f2bf(a.z*sc); f[3]=f2bf(a.w*sc);
            f[4]=f2bf(b.x*sc); f[5]=f2bf(b.y*sc); f[6]=f2bf(b.z*sc); f[7]=f2bf(b.w*sc);
            AX[m][0] = f;
        }
        {   // x-weights, k 32..63 (act + bias slot + zeros)
            short8 f;
#pragma unroll
            for (int i = 0; i < 8; ++i) {
                int k = 32 + 8 * q + i;
                float v = 0.f;
                if (k < 36)       v = W_ih[(size_t)g * 36 + k];
                else if (k == 36) v = b_ih[g] + (g < 128 ? b_hh[g] : 0.f);
                f[i] = f2bf(v * sc);
            }
            AX[m][1] = f;
        }
#pragma unroll
        for (int kk = 0; kk < 2; ++kk) {     // h-weights
            const float* wp = W_hh + (size_t)g * HH + 32 * kk + 8 * q;
            float4 a = *(const float4*)wp, b = *(const float4*)(wp + 4);
            short8 f;
            f[0]=f2bf(a.x*sc); f[1]=f2bf(a.y*sc); f[2]=f2bf(a.z*sc); f[3]=f2bf(a.w*sc);
            f[4]=f2bf(b.x*sc); f[5]=f2bf(b.y*sc); f[6]=f2bf(b.z*sc); f[7]=f2bf(b.w*sc);
            AH[m][kk] = f;
        }
    }
    short8 AR[2];                            // reward tile: A-row 0 = W_r (unscaled)
#pragma unroll
    for (int kk = 0; kk < 2; ++kk) {
        short8 f;
#pragma unroll
        for (int i = 0; i < 8; ++i) {
            int k = 32 * kk + 8 * q + i;
            f[i] = (c == 0) ? (short)f2bf(W_r[k]) : (short)0;
        }
        AR[kk] = f;
    }

    f32x4 bhn4;                              // Cnh C-init: 2*L2E * b_hh[n-rows]
#pragma unroll
    for (int reg = 0; reg < 4; ++reg) bhn4[reg] = b_hh[128 + u0 + reg] * (2.0f * L2E);
    const float brr = b_r[0];

    // ---- LDS byte offsets (same swizzles as r14, per stream buffer) ----
    const int swz = c & 7;
    const int wraddr  = c * 128 + ((((u0 >> 3)) ^ swz) << 4) + (u0 & 7) * 2;
    const int rdaddr0 = c * 128 + ((q ^ swz) << 4);          // units 8q..8q+7
    const int rdaddr1 = c * 128 + (((4 + q) ^ swz) << 4);    // units 32+8q..+7
    const int f32addr = c * 256 + (((4 * w + q) ^ swz) << 4);

    // ---- x stream base pointers: stream X = seq bid*32+c, Y = bid*32+16+c ----
    const unsigned short* pxX = xext + ((size_t)(bid * 32 + c) * TT) * 40;
    const unsigned short* pxY = xext + ((size_t)(bid * 32 + 16 + c) * TT) * 40;

    const short8 zero8 = {0, 0, 0, 0, 0, 0, 0, 0};
    const f32x4 zf = {0.f, 0.f, 0.f, 0.f};

    // ---- init: zero all h buffers; prime per-set, per-stream x/gi state ----
    ((uint2*)hbX)[tid] = make_uint2(0u, 0u);           // 512 x 8B = 4KB
    ((uint2*)hbY)[tid] = make_uint2(0u, 0u);
    ((f32x4*)hfX)[tid] = zf;                           // 512 x 16B = 8KB
    ((f32x4*)hfY)[tid] = zf;
    short8 xoX, xaX, xoY, xaY;
    f32x4 cgrX = zf, cgzX = zf, cgnX = zf, cgrY = zf, cgzY = zf, cgnY = zf;
    if (set == 0) {
        LOADX(pxX, xoX, xaX, 0)
        LOADX(pxY, xoY, xaY, 0)
        cgrX = MFMA(AX[0][1], xaX, MFMA(AX[0][0], xoX, zf));   // gi(0)
        cgrY = MFMA(AX[0][1], xaY, MFMA(AX[0][0], xoY, zf));
        cgzX = MFMA(AX[1][1], xaX, MFMA(AX[1][0], xoX, zf));
        cgzY = MFMA(AX[1][1], xaY, MFMA(AX[1][0], xoY, zf));
        cgnX = MFMA(AX[2][1], xaX, MFMA(AX[2][0], xoX, zf));
        cgnY = MFMA(AX[2][1], xaY, MFMA(AX[2][0], xoY, zf));
        LOADX(pxX, xoX, xaX, 2)             // x(2) -> rings
        LOADX(pxY, xoY, xaY, 2)
    } else {
        LOADX(pxX, xoX, xaX, 1)             // x(1) -> rings (gi(1) built in light)
        LOADX(pxY, xoY, xaY, 1)
    }
    f32x4 holdX = zf, holdY = zf;
    asm volatile("s_waitcnt lgkmcnt(0)" ::: "memory");
    __builtin_amdgcn_s_barrier();
    asm volatile("" ::: "memory");

    float* rew = out + (size_t)BB * HH;      // out: [h_final B*H][rewards B*T]

#pragma unroll 1
    for (int it = 0; it < TT / 2; ++it) {
        const int Ta = 2 * it, Tb = 2 * it + 1;
        // half 1: A heavy (step Ta, X+Y), B light (gi for Tb, X+Y)
        if (set == 0) { HEAVY(0, Ta, it) } else { LIGHT(Tb) }
        __builtin_amdgcn_s_barrier();
        asm volatile("" ::: "memory");
        // half 2: B heavy (step Tb, X+Y), A light (gi for Ta+2, X+Y)
        if (set == 1) { HEAVY(1, Tb, it) } else { LIGHT(Ta + 2) }
        __builtin_amdgcn_s_barrier();
        asm volatile("" ::: "memory");
    }

    // ---- epilogue: h(T-1) in parity-0 buffers / set B's hold ----
    if (set == 1) {
        if (w == 3) {
            short8 Ax0 = *(const short8*)((const char*)hbX[0] + rdaddr0);
            short8 Ax1 = *(const short8*)((const char*)hbX[0] + rdaddr1);
            short8 Ay0 = *(const short8*)((const char*)hbY[0] + rdaddr0);
            short8 Ay1 = *(const short8*)((const char*)hbY[0] + rdaddr1);
            f32x4 CrwX = MFMA(AR[1], Ax1, MFMA(AR[0], Ax0, zf));
            f32x4 CrwY = MFMA(AR[1], Ay1, MFMA(AR[0], Ay0, zf));
            if (q == 0) {
                rew[(size_t)(bid * 32 + c) * TT + TT - 1]      = CrwX[0] + brr;
                rew[(size_t)(bid * 32 + 16 + c) * TT + TT - 1] = CrwY[0] + brr;
            }
        }
        *(float4*)(out + (size_t)(bid * 32 + c) * HH + u0) =
            make_float4(holdX[0], holdX[1], holdX[2], holdX[3]);
        *(float4*)(out + (size_t)(bid * 32 + 16 + c) * HH + u0) =
            make_float4(holdY[0], holdY[1], holdY[2], holdY[3]);
    }
}

// ---- fallback: round-9 single-set kernel reading raw obs/act (no ws) ----
__global__ __launch_bounds__(64, 1)
void gru_wave_fb(const float* __restrict__ obs, const float* __restrict__ action,
                 const float* __restrict__ W_ih, const float* __restrict__ b_ih,
                 const float* __restrict__ W_hh, const float* __restrict__ b_hh,
                 const float* __restrict__ W_r, const float* __restrict__ b_r,
                 float* __restrict__ out)
{
    // simple correct fallback (round-2 structure): one wave per sequence
    const int b = blockIdx.x, j = threadIdx.x;
    float wir[36], wiz[36], win[36];
#pragma unroll
    for (int d = 0; d < 36; ++d) {
        wir[d] = W_ih[(size_t)(0 * HH + j) * 36 + d];
        wiz[d] = W_ih[(size_t)(1 * HH + j) * 36 + d];
        win[d] = W_ih[(size_t)(2 * HH + j) * 36 + d];
    }
    float whr[HH], whz[HH], whn[HH];
#pragma unroll
    for (int k = 0; k < HH; ++k) {
        whr[k] = W_hh[(size_t)(0 * HH + j) * HH + k];
        whz[k] = W_hh[(size_t)(1 * HH + j) * HH + k];
        whn[k] = W_hh[(size_t)(2 * HH + j) * HH + k];
    }
    const float bir = b_ih[j], biz = b_ih[HH + j], bin = b_ih[2 * HH + j];
    const float bhr = b_hh[j], bhz = b_hh[HH + j], bhn = b_hh[2 * HH + j];
    const float wr = W_r[j], br = b_r[0];
    float h = 0.f;
    float* rew = out + (size_t)BB * HH;
    for (int t = 0; t < TT; ++t) {
        float x[36];
#pragma unroll
        for (int d = 0; d < DOBS; ++d) x[d] = obs[((size_t)b * TT + t) * DOBS + d];
#pragma unroll
        for (int d = 0; d < DACT; ++d) x[32 + d] = action[((size_t)b * TT + t) * DACT + d];
        float gr = bir + bhr, gz = biz + bhz, gn = bin, an = bhn;
#pragma unroll
        for (int d = 0; d < 36; ++d) { gr += wir[d]*x[d]; gz += wiz[d]*x[d]; gn += win[d]*x[d]; }
#pragma unroll
        for (int k = 0; k < HH; ++k) {
            float hk = __int_as_float(__builtin_amdgcn_readlane(__float_as_int(h), k));
            gr += whr[k]*hk; gz += whz[k]*hk; an += whn[k]*hk;
        }
        float r = frcp(1.f + __expf(-gr)), z = frcp(1.f + __expf(-gz));
        float n = 1.f - 2.f*frcp(__expf(2.f*(gn + r*an)) + 1.f);
        h = n + z*(h - n);
        float pr = h * wr;
#pragma unroll
        for (int m = 1; m < 64; m <<= 1) pr += __shfl_xor(pr, m, 64);
        if (j == 0) rew[(size_t)b * TT + t] = pr + br;
    }
    out[(size_t)b * HH + j] = h;
}

// ------------------------------------------------------------------- host ---
extern "C" void kernel_launch(void* const* d_in, const int* in_sizes, int n_in,
                              void* d_out, int out_size, void* d_ws, size_t ws_size,
                              hipStream_t stream)
{
    const float* obs    = (const float*)d_in[0];
    const float* action = (const float*)d_in[1];
    const float* W_ih   = (const float*)d_in[2];
    const float* b_ih   = (const float*)d_in[3];
    const float* W_hh   = (const float*)d_in[4];
    const float* b_hh   = (const float*)d_in[5];
    const float* W_r    = (const float*)d_in[6];
    const float* b_r    = (const float*)d_in[7];
    float* out          = (float*)d_out;

    // xext (80 MB) + slack rows so the unclamped t+4 prefetch stays in ws.
    const size_t xext_bytes = ((size_t)BB * TT + 8) * 40 * sizeof(unsigned short);
    if (ws_size >= xext_bytes) {
        unsigned short* xext = (unsigned short*)d_ws;
        pack_x<<<dim3((BB * TT) / 256), dim3(256), 0, stream>>>(obs, action, xext);
        gru_fused<<<dim3(BB / 32), dim3(512), 0, stream>>>(
            xext, W_ih, b_ih, W_hh, b_hh, W_r, b_r, out);
    } else {
        gru_wave_fb<<<dim3(BB), dim3(64), 0, stream>>>(
            obs, action, W_ih, b_ih, W_hh, b_hh, W_r, b_r, out);
    }
}

// Round 17
// 427.372 us; speedup vs baseline: 1.4666x; 1.4666x over previous
//
#include <hip/hip_runtime.h>

// GRU reward model, round 17: r15 structure, pack_x ELIMINATED.
//   B=1024 seqs, T=1024 steps, Din=36 (obs32+act4+bias), H=64, gates 3H=192.
//   64 blocks x 512 threads (8 waves = 2/SIMD); block owns 16 sequences.
//   Set A (waves 0-3) owns EVEN steps, set B (waves 4-7) ODD steps.
//   h carried in LDS: hbuf[2] bf16 (MFMA fragments) + hf32[2] fp32 (lossless).
//   One s_barrier per step; vmcnt never drains across barriers.
//   NEW: x is read as RAW fp32 (no pre-pack kernel). LIGHT keeps the raw
//   float4s in registers one extra phase and converts with v_cvt_pk_bf16_f32
//   (same RNE op as the h path) -> converts are >860 cyc off the chain
//   (r7's in-step convert stall cannot occur). Saves the 33 us pack_x
//   dispatch + 160 MB of ws traffic; chain code is byte-identical to r15.

#define BB 1024
#define TT 1024
#define DOBS 32
#define DACT 4
#define HH 64

typedef __attribute__((ext_vector_type(8))) short short8;
typedef __attribute__((ext_vector_type(4))) float f32x4;

#define MFMA(A, B, C) __builtin_amdgcn_mfma_f32_16x16x32_bf16((A), (B), (C), 0, 0, 0)

static __device__ __forceinline__ unsigned short f2bf(float f) {
    unsigned u = __float_as_uint(f);
    u += 0x7fffu + ((u >> 16) & 1u);   // RNE
    return (unsigned short)(u >> 16);
}
static __device__ __forceinline__ float frcp(float x) { return __builtin_amdgcn_rcpf(x); }
static __device__ __forceinline__ unsigned cvt_pk(float lo, float hi) {
    unsigned r;
    asm("v_cvt_pk_bf16_f32 %0, %1, %2" : "=v"(r) : "v"(lo), "v"(hi));
    return r;
}

#define L2E 1.442695040888963f

// LOADR: issue raw fp32 loads for x(T2) into rawA/rawB (+rawC on q==0).
#define LOADR(T2)                                                              \
  {                                                                            \
    const int tc_ = (T2) < TT ? (T2) : TT - 1;                                 \
    const float* op_ = po + (size_t)tc_ * DOBS + 8 * q;                        \
    rawA = *(const float4*)op_;                                                \
    rawB = *(const float4*)(op_ + 4);                                          \
    if (q == 0) rawC = *(const float4*)(pa + (size_t)tc_ * DACT);              \
  }

// CVTX: convert the raw regs (loaded >=1 phase ago) into B-fragments.
#define CVTX(XO, XA)                                                           \
  {                                                                            \
    uint4 u_ = make_uint4(cvt_pk(rawA.x, rawA.y), cvt_pk(rawA.z, rawA.w),      \
                          cvt_pk(rawB.x, rawB.y), cvt_pk(rawB.z, rawB.w));     \
    XO = *(short8*)&u_;                                                        \
    if (q == 0) {                                                              \
      uint4 v_ = make_uint4(cvt_pk(rawC.x, rawC.y), cvt_pk(rawC.z, rawC.w),    \
                            0x3f80u, 0u);          /* bias 1.0 at k=36 */      \
      XA = *(short8*)&v_;                                                      \
    } else XA = zero8;                                                         \
  }

// HEAVY: h-dependent step work, at wave priority 1. PH literal.
// h(T-1) fp32 via hf32[PH] (own 4 units, lossless); bf16 hbuf -> MFMA frags.
// Weights pre-scaled: Cr,Cz = -L2E*preact; Cnh,cgn = 2*L2E*preact parts.
#define HEAVY(PH, T, IT)                                                       \
  {                                                                            \
    __builtin_amdgcn_s_setprio(1);                                             \
    short8 Ah0 = *(const short8*)((const char*)hbuf[PH] + rdaddr0);            \
    short8 Ah1 = *(const short8*)((const char*)hbuf[PH] + rdaddr1);            \
    f32x4 hp = *(const f32x4*)((const char*)hf32[PH] + f32addr);               \
    f32x4 Cr  = MFMA(AH[0][1], Ah1, MFMA(AH[0][0], Ah0, cgr));                 \
    f32x4 Cz  = MFMA(AH[1][1], Ah1, MFMA(AH[1][0], Ah0, cgz));                 \
    f32x4 Cnh = MFMA(AH[2][1], Ah1, MFMA(AH[2][0], Ah0, bhn4));                \
    f32x4 Crw = zf;                                                            \
    const bool dorw_ = (w == ((IT) & 3));                                      \
    if (dorw_) Crw = MFMA(AR[1], Ah1, MFMA(AR[0], Ah0, zf));                   \
    _Pragma("unroll")                                                          \
    for (int reg = 0; reg < 4; ++reg) {                                        \
      float rr   = frcp(1.0f + __builtin_amdgcn_exp2f(Cr[reg]));               \
      float zz   = frcp(1.0f + __builtin_amdgcn_exp2f(Cz[reg]));               \
      float E    = __builtin_amdgcn_exp2f(__builtin_fmaf(rr, Cnh[reg], cgn[reg])); \
      float nn   = __builtin_fmaf(-2.0f, frcp(E + 1.0f), 1.0f);                \
      hold[reg]  = __builtin_fmaf(zz, hp[reg] - nn, nn);                       \
    }                                                                          \
    unsigned pk0 = cvt_pk(hold[0], hold[1]);                                   \
    unsigned pk1 = cvt_pk(hold[2], hold[3]);                                   \
    *(uint2*)((char*)hbuf[PH ^ 1] + wraddr) = make_uint2(pk0, pk1);            \
    *(f32x4*)((char*)hf32[PH ^ 1] + f32addr) = hold;                           \
    if (dorw_ && q == 0 && (T) > 0)                                            \
      rew[(size_t)(bid * 16 + c) * TT + (T) - 1] = Crw[0] + brr;               \
    asm volatile("s_waitcnt lgkmcnt(0)" ::: "memory");                         \
    __builtin_amdgcn_s_setprio(0);                                             \
  }

// LIGHT(T2): gi(T2) from frags (=x(T2)); frags <- cvt(raw) (=x(T2+2));
// raw <- load x(T2+4). All off the h-chain; hidden under partner's HEAVY.
#define LIGHT(T2)                                                              \
  {                                                                            \
    cgr = MFMA(AX[0][1], xa, MFMA(AX[0][0], xo, zf));                          \
    cgz = MFMA(AX[1][1], xa, MFMA(AX[1][0], xo, zf));                          \
    cgn = MFMA(AX[2][1], xa, MFMA(AX[2][0], xo, zf));                          \
    CVTX(xo, xa)                                                               \
    LOADR((T2) + 4)                                                            \
  }

__global__ __launch_bounds__(512, 1)
void gru_fused(const float* __restrict__ obs, const float* __restrict__ act,
               const float* __restrict__ W_ih, const float* __restrict__ b_ih,
               const float* __restrict__ W_hh, const float* __restrict__ b_hh,
               const float* __restrict__ W_r, const float* __restrict__ b_r,
               float* __restrict__ out)
{
    const int tid = threadIdx.x;
    const int set = tid >> 8;                // 0: even steps, 1: odd steps
    const int w = (tid >> 6) & 3;            // wave-in-set
    const int l = tid & 63, c = l & 15, q = l >> 4;
    const int bid = blockIdx.x;
    const int u0 = 16 * w + 4 * q;           // first of this lane's 4 units

    __shared__ __align__(16) unsigned short hbuf[2][16 * 64];  // bf16 [seq][unit]
    __shared__ __align__(16) float          hf32[2][16 * 64];  // fp32 [seq][unit]

    // ---- weight A-fragments, PRE-SCALED for the gate exp2s ----
    //   m=0 (r), m=1 (z): rows * -L2E;  m=2 (n): rows * +2*L2E.
    short8 AX[3][2], AH[3][2];
#pragma unroll
    for (int m = 0; m < 3; ++m) {
        const float sc = (m == 2) ? (2.0f * L2E) : (-L2E);
        const int j = w + 4 * m;             // tile: w=r, w+4=z, w+8=n
        const int g = 16 * j + c;            // gate row (A-row = c)
        {   // x-weights, k 0..31
            const float* wp = W_ih + (size_t)g * 36 + 8 * q;
            float4 a = *(const float4*)wp, b = *(const float4*)(wp + 4);
            short8 f;
            f[0]=f2bf(a.x*sc); f[1]=f2bf(a.y*sc); f[2]=f2bf(a.z*sc); f[3]=f2bf(a.w*sc);
            f[4]=f2bf(b.x*sc); f[5]=f2bf(b.y*sc); f[6]=f2bf(b.z*sc); f[7]=f2bf(b.w*sc);
            AX[m][0] = f;
        }
        {   // x-weights, k 32..63 (act + bias slot + zeros)
            short8 f;
#pragma unroll
            for (int i = 0; i < 8; ++i) {
                int k = 32 + 8 * q + i;
                float v = 0.f;
                if (k < 36)       v = W_ih[(size_t)g * 36 + k];
                else if (k == 36) v = b_ih[g] + (g < 128 ? b_hh[g] : 0.f);
                f[i] = f2bf(v * sc);
            }
            AX[m][1] = f;
        }
#pragma unroll
        for (int kk = 0; kk < 2; ++kk) {     // h-weights
            const float* wp = W_hh + (size_t)g * HH + 32 * kk + 8 * q;
            float4 a = *(const float4*)wp, b = *(const float4*)(wp + 4);
            short8 f;
            f[0]=f2bf(a.x*sc); f[1]=f2bf(a.y*sc); f[2]=f2bf(a.z*sc); f[3]=f2bf(a.w*sc);
            f[4]=f2bf(b.x*sc); f[5]=f2bf(b.y*sc); f[6]=f2bf(b.z*sc); f[7]=f2bf(b.w*sc);
            AH[m][kk] = f;
        }
    }
    short8 AR[2];                            // reward tile: A-row 0 = W_r (unscaled)
#pragma unroll
    for (int kk = 0; kk < 2; ++kk) {
        short8 f;
#pragma unroll
        for (int i = 0; i < 8; ++i) {
            int k = 32 * kk + 8 * q + i;
            f[i] = (c == 0) ? (short)f2bf(W_r[k]) : (short)0;
        }
        AR[kk] = f;
    }

    f32x4 bhn4;                              // Cnh C-init: 2*L2E * b_hh[n-rows]
#pragma unroll
    for (int reg = 0; reg < 4; ++reg) bhn4[reg] = b_hh[128 + u0 + reg] * (2.0f * L2E);
    const float brr = b_r[0];

    // ---- LDS byte offsets ----
    const int swz = c & 7;
    const int wraddr  = c * 128 + ((((u0 >> 3)) ^ swz) << 4) + (u0 & 7) * 2;
    const int rdaddr0 = c * 128 + ((q ^ swz) << 4);          // units 8q..8q+7
    const int rdaddr1 = c * 128 + (((4 + q) ^ swz) << 4);    // units 32+8q..+7
    const int f32addr = c * 256 + (((4 * w + q) ^ swz) << 4);

    // ---- raw x stream base pointers (lane's seq = c) ----
    const size_t row = (size_t)(bid * 16 + c) * TT;
    const float* po = obs + row * DOBS;
    const float* pa = act + row * DACT;

    const short8 zero8 = {0, 0, 0, 0, 0, 0, 0, 0};
    const f32x4 zf = {0.f, 0.f, 0.f, 0.f};

    // ---- init: zero h buffers; prime per-set raw/frag/gi state ----
    ((uint2*)hbuf)[tid] = make_uint2(0u, 0u);          // 512 x 8B = 4KB
    ((f32x4*)hf32)[tid] = zf;                          // 512 x 16B = 8KB
    float4 rawA = make_float4(0,0,0,0), rawB = rawA, rawC = rawA;
    short8 xo, xa;
    f32x4 cgr = zf, cgz = zf, cgn = zf;
    if (set == 0) {
        LOADR(0) CVTX(xo, xa)               // frags = x(0)
        cgr = MFMA(AX[0][1], xa, MFMA(AX[0][0], xo, zf));   // gi(0)
        cgz = MFMA(AX[1][1], xa, MFMA(AX[1][0], xo, zf));
        cgn = MFMA(AX[2][1], xa, MFMA(AX[2][0], xo, zf));
        LOADR(2) CVTX(xo, xa)               // frags = x(2)
        LOADR(4)                            // raw = x(4), cvt'd in LIGHT(2)
    } else {
        LOADR(1) CVTX(xo, xa)               // frags = x(1)
        LOADR(3)                            // raw = x(3), cvt'd in LIGHT(1)
    }
    f32x4 hold = zf;
    asm volatile("s_waitcnt lgkmcnt(0)" ::: "memory");
    __builtin_amdgcn_s_barrier();
    asm volatile("" ::: "memory");

    float* rew = out + (size_t)BB * HH;      // out: [h_final B*H][rewards B*T]

#pragma unroll 1
    for (int it = 0; it < TT / 2; ++it) {
        const int Ta = 2 * it, Tb = 2 * it + 1;
        // half 1: A heavy (step Ta) @prio1, B light (gi for Tb) @prio0
        if (set == 0) { HEAVY(0, Ta, it) } else { LIGHT(Tb) }
        __builtin_amdgcn_s_barrier();
        asm volatile("" ::: "memory");
        // half 2: B heavy (step Tb) @prio1, A light (gi for Ta+2) @prio0
        if (set == 1) { HEAVY(1, Tb, it) } else { LIGHT(Ta + 2) }
        __builtin_amdgcn_s_barrier();
        asm volatile("" ::: "memory");
    }

    // ---- epilogue: h(T-1) is in hbuf[0]/hold of set B (T-1 = 1023 odd) ----
    if (set == 1) {
        if (w == 3) {
            short8 Ah0 = *(const short8*)((const char*)hbuf[0] + rdaddr0);
            short8 Ah1 = *(const short8*)((const char*)hbuf[0] + rdaddr1);
            f32x4 Crw = MFMA(AR[0], Ah0, zf);
            Crw = MFMA(AR[1], Ah1, Crw);
            if (q == 0)
                rew[(size_t)(bid * 16 + c) * TT + TT - 1] = Crw[0] + brr;
        }
        *(float4*)(out + (size_t)(bid * 16 + c) * HH + u0) =
            make_float4(hold[0], hold[1], hold[2], hold[3]);
    }
}

// ------------------------------------------------------------------- host ---
extern "C" void kernel_launch(void* const* d_in, const int* in_sizes, int n_in,
                              void* d_out, int out_size, void* d_ws, size_t ws_size,
                              hipStream_t stream)
{
    const float* obs    = (const float*)d_in[0];
    const float* action = (const float*)d_in[1];
    const float* W_ih   = (const float*)d_in[2];
    const float* b_ih   = (const float*)d_in[3];
    const float* W_hh   = (const float*)d_in[4];
    const float* b_hh   = (const float*)d_in[5];
    const float* W_r    = (const float*)d_in[6];
    const float* b_r    = (const float*)d_in[7];
    float* out          = (float*)d_out;

    gru_fused<<<dim3(BB / 16), dim3(512), 0, stream>>>(
        obs, action, W_ih, b_ih, W_hh, b_hh, W_r, b_r, out);
}

// Round 18
// 373.161 us; speedup vs baseline: 1.6796x; 1.1453x over previous
//
#include <hip/hip_runtime.h>

// GRU reward model, round 18: r15 structure + linear private hf32 + reward
// offloaded to the LIGHT set.
//   B=1024 seqs, T=1024 steps, Din=36 (obs32+act4+bias), H=64, gates 3H=192.
//   64 blocks x 512 threads (8 waves = 2/SIMD); block owns 16 sequences.
//   Set A (waves 0-3) owns EVEN steps, set B (waves 4-7) ODD steps.
//   h carried in LDS: hbuf[2] bf16 (MFMA fragments, XOR-swizzled) + hf32[2]
//   fp32. NEW: hf32 is addressed linearly by set-lane ((w*64+l)*16) -- each
//   lane round-trips only its OWN 4 units, so a wave's b128 access is 1024
//   contiguous bytes: zero bank conflicts (was c*256+slot: 2.1M conflicts).
//   NEW: reward(T-1) = h(T-1).W_r is computed by the idle LIGHT set from the
//   stable hbuf parity (same bf16 fragments -> bit-identical), removing the
//   2-MFMA + store straggler from HEAVY's barrier-synced wall.
//   One s_barrier per step; vmcnt never drains across barriers.

#define BB 1024
#define TT 1024
#define DOBS 32
#define DACT 4
#define HH 64

typedef __attribute__((ext_vector_type(8))) short short8;
typedef __attribute__((ext_vector_type(4))) float f32x4;

#define MFMA(A, B, C) __builtin_amdgcn_mfma_f32_16x16x32_bf16((A), (B), (C), 0, 0, 0)

static __device__ __forceinline__ unsigned short f2bf(float f) {
    unsigned u = __float_as_uint(f);
    u += 0x7fffu + ((u >> 16) & 1u);   // RNE
    return (unsigned short)(u >> 16);
}
static __device__ __forceinline__ float frcp(float x) { return __builtin_amdgcn_rcpf(x); }
static __device__ __forceinline__ unsigned cvt_pk(float lo, float hi) {
    unsigned r;
    asm("v_cvt_pk_bf16_f32 %0, %1, %2" : "=v"(r) : "v"(lo), "v"(hi));
    return r;
}

#define L2E 1.442695040888963f

// ---- pre-kernel: xext[(b*TT+t)*40] = bf16 [obs(32), act(4), 1.0, 0,0,0] ----
__global__ __launch_bounds__(256)
void pack_x(const float* __restrict__ obs, const float* __restrict__ act,
            unsigned short* __restrict__ xext)
{
    const size_t r = (size_t)blockIdx.x * 256 + threadIdx.x;   // (b,t) row
    const float* o = obs + r * DOBS;
    unsigned short* d = xext + r * 40;
    short8 v[5];
#pragma unroll
    for (int j = 0; j < 4; ++j) {
        float4 a = ((const float4*)o)[2 * j];
        float4 b = ((const float4*)o)[2 * j + 1];
        short8 t;
        t[0]=f2bf(a.x); t[1]=f2bf(a.y); t[2]=f2bf(a.z); t[3]=f2bf(a.w);
        t[4]=f2bf(b.x); t[5]=f2bf(b.y); t[6]=f2bf(b.z); t[7]=f2bf(b.w);
        v[j] = t;
    }
    {
        float4 a = *(const float4*)(act + r * DACT);
        short8 t;
        t[0]=f2bf(a.x); t[1]=f2bf(a.y); t[2]=f2bf(a.z); t[3]=f2bf(a.w);
        t[4]=(short)0x3f80; t[5]=0; t[6]=0; t[7]=0;   // bias slot k=36
        v[4] = t;
    }
#pragma unroll
    for (int j = 0; j < 5; ++j) ((short8*)d)[j] = v[j];
}

// LOADX: fetch x(t) B-fragments (seq = c). PACKED: no clamp (ws slack rows).
#define LOADX(XO, XA, T)                                                       \
  {                                                                            \
    if (PACKED) {                                                              \
      XO = *(const short8*)(px + (size_t)(T) * 40 + 8 * q);                    \
      XA = (q == 0) ? *(const short8*)(px + (size_t)(T) * 40 + 32) : zero8;    \
    } else {                                                                   \
      const int tc_ = (T) < TT ? (T) : TT - 1;                                 \
      const float* op_ = po + (size_t)tc_ * DOBS + 8 * q;                      \
      float4 a_ = *(const float4*)op_, b_ = *(const float4*)(op_ + 4);         \
      short8 f_;                                                               \
      f_[0]=f2bf(a_.x); f_[1]=f2bf(a_.y); f_[2]=f2bf(a_.z); f_[3]=f2bf(a_.w);  \
      f_[4]=f2bf(b_.x); f_[5]=f2bf(b_.y); f_[6]=f2bf(b_.z); f_[7]=f2bf(b_.w);  \
      XO = f_;                                                                 \
      if (q == 0) {                                                            \
        float4 av_ = *(const float4*)(pa + (size_t)tc_ * DACT);                \
        short8 g_;                                                             \
        g_[0]=f2bf(av_.x); g_[1]=f2bf(av_.y); g_[2]=f2bf(av_.z);               \
        g_[3]=f2bf(av_.w); g_[4]=(short)0x3f80; g_[5]=0; g_[6]=0; g_[7]=0;     \
        XA = g_;                                                               \
      } else XA = zero8;                                                       \
    }                                                                          \
  }

// HEAVY: h-dependent step work at prio 1. PH literal. No reward (moved to LIGHT).
// Weights pre-scaled: Cr,Cz = -L2E*preact; Cnh,cgn = 2*L2E*preact parts.
#define HEAVY(PH, T)                                                           \
  {                                                                            \
    __builtin_amdgcn_s_setprio(1);                                             \
    short8 Ah0 = *(const short8*)((const char*)hbuf[PH] + rdaddr0);            \
    short8 Ah1 = *(const short8*)((const char*)hbuf[PH] + rdaddr1);            \
    f32x4 hp = *(const f32x4*)((const char*)hf32[PH] + f32addr);               \
    f32x4 Cr  = MFMA(AH[0][1], Ah1, MFMA(AH[0][0], Ah0, cgr));                 \
    f32x4 Cz  = MFMA(AH[1][1], Ah1, MFMA(AH[1][0], Ah0, cgz));                 \
    f32x4 Cnh = MFMA(AH[2][1], Ah1, MFMA(AH[2][0], Ah0, bhn4));                \
    _Pragma("unroll")                                                          \
    for (int reg = 0; reg < 4; ++reg) {                                        \
      float rr   = frcp(1.0f + __builtin_amdgcn_exp2f(Cr[reg]));               \
      float zz   = frcp(1.0f + __builtin_amdgcn_exp2f(Cz[reg]));               \
      float E    = __builtin_amdgcn_exp2f(__builtin_fmaf(rr, Cnh[reg], cgn[reg])); \
      float nn   = __builtin_fmaf(-2.0f, frcp(E + 1.0f), 1.0f);                \
      hold[reg]  = __builtin_fmaf(zz, hp[reg] - nn, nn);                       \
    }                                                                          \
    unsigned pk0 = cvt_pk(hold[0], hold[1]);                                   \
    unsigned pk1 = cvt_pk(hold[2], hold[3]);                                   \
    *(uint2*)((char*)hbuf[PH ^ 1] + wraddr) = make_uint2(pk0, pk1);            \
    *(f32x4*)((char*)hf32[PH ^ 1] + f32addr) = hold;                           \
    asm volatile("s_waitcnt lgkmcnt(0)" ::: "memory");                         \
    __builtin_amdgcn_s_setprio(0);                                             \
  }

// LIGHT: gi(T2) from the x ring; refill ring (T2+2); and compute reward(TR-1)
// from the STABLE parity hbuf[PH] (bit-identical to the old HEAVY reward).
#define LIGHT(T2, PH, TR, IT)                                                  \
  {                                                                            \
    cgr = MFMA(AX[0][1], xa, MFMA(AX[0][0], xo, zf));                          \
    cgz = MFMA(AX[1][1], xa, MFMA(AX[1][0], xo, zf));                          \
    cgn = MFMA(AX[2][1], xa, MFMA(AX[2][0], xo, zf));                          \
    LOADX(xo, xa, (T2) + 2)                                                    \
    if (w == ((IT) & 3) && (TR) > 0) {                                         \
      short8 Lh0 = *(const short8*)((const char*)hbuf[PH] + rdaddr0);          \
      short8 Lh1 = *(const short8*)((const char*)hbuf[PH] + rdaddr1);          \
      f32x4 Crw = MFMA(AR[1], Lh1, MFMA(AR[0], Lh0, zf));                      \
      if (q == 0)                                                              \
        rew[(size_t)(bid * 16 + c) * TT + (TR) - 1] = Crw[0] + brr;            \
    }                                                                          \
  }

template<bool PACKED>
__global__ __launch_bounds__(512, 1)
void gru_fused(const unsigned short* __restrict__ xext,
               const float* __restrict__ obs, const float* __restrict__ act,
               const float* __restrict__ W_ih, const float* __restrict__ b_ih,
               const float* __restrict__ W_hh, const float* __restrict__ b_hh,
               const float* __restrict__ W_r, const float* __restrict__ b_r,
               float* __restrict__ out)
{
    const int tid = threadIdx.x;
    const int set = tid >> 8;                // 0: even steps, 1: odd steps
    const int w = (tid >> 6) & 3;            // wave-in-set
    const int l = tid & 63, c = l & 15, q = l >> 4;
    const int bid = blockIdx.x;
    const int u0 = 16 * w + 4 * q;           // first of this lane's 4 units

    __shared__ __align__(16) unsigned short hbuf[2][16 * 64];  // bf16 [seq][unit]
    __shared__ __align__(16) float          hf32[2][16 * 64];  // fp32, lane-linear

    // ---- weight A-fragments, PRE-SCALED for the gate exp2s ----
    //   m=0 (r), m=1 (z): rows * -L2E;  m=2 (n): rows * +2*L2E.
    short8 AX[3][2], AH[3][2];
#pragma unroll
    for (int m = 0; m < 3; ++m) {
        const float sc = (m == 2) ? (2.0f * L2E) : (-L2E);
        const int j = w + 4 * m;             // tile: w=r, w+4=z, w+8=n
        const int g = 16 * j + c;            // gate row (A-row = c)
        {   // x-weights, k 0..31
            const float* wp = W_ih + (size_t)g * 36 + 8 * q;
            float4 a = *(const float4*)wp, b = *(const float4*)(wp + 4);
            short8 f;
            f[0]=f2bf(a.x*sc); f[1]=f2bf(a.y*sc); f[2]=f2bf(a.z*sc); f[3]=f2bf(a.w*sc);
            f[4]=f2bf(b.x*sc); f[5]=f2bf(b.y*sc); f[6]=f2bf(b.z*sc); f[7]=f2bf(b.w*sc);
            AX[m][0] = f;
        }
        {   // x-weights, k 32..63 (act + bias slot + zeros)
            short8 f;
#pragma unroll
            for (int i = 0; i < 8; ++i) {
                int k = 32 + 8 * q + i;
                float v = 0.f;
                if (k < 36)       v = W_ih[(size_t)g * 36 + k];
                else if (k == 36) v = b_ih[g] + (g < 128 ? b_hh[g] : 0.f);
                f[i] = f2bf(v * sc);
            }
            AX[m][1] = f;
        }
#pragma unroll
        for (int kk = 0; kk < 2; ++kk) {     // h-weights
            const float* wp = W_hh + (size_t)g * HH + 32 * kk + 8 * q;
            float4 a = *(const float4*)wp, b = *(const float4*)(wp + 4);
            short8 f;
            f[0]=f2bf(a.x*sc); f[1]=f2bf(a.y*sc); f[2]=f2bf(a.z*sc); f[3]=f2bf(a.w*sc);
            f[4]=f2bf(b.x*sc); f[5]=f2bf(b.y*sc); f[6]=f2bf(b.z*sc); f[7]=f2bf(b.w*sc);
            AH[m][kk] = f;
        }
    }
    short8 AR[2];                            // reward tile: A-row 0 = W_r (unscaled)
#pragma unroll
    for (int kk = 0; kk < 2; ++kk) {
        short8 f;
#pragma unroll
        for (int i = 0; i < 8; ++i) {
            int k = 32 * kk + 8 * q + i;
            f[i] = (c == 0) ? (short)f2bf(W_r[k]) : (short)0;
        }
        AR[kk] = f;
    }

    f32x4 bhn4;                              // Cnh C-init: 2*L2E * b_hh[n-rows]
#pragma unroll
    for (int reg = 0; reg < 4; ++reg) bhn4[reg] = b_hh[128 + u0 + reg] * (2.0f * L2E);
    const float brr = b_r[0];

    // ---- LDS byte offsets ----
    // hbuf: XOR swizzle on 16B slots within 128B seq-rows (proven benign).
    const int swz = c & 7;
    const int wraddr  = c * 128 + ((((u0 >> 3)) ^ swz) << 4) + (u0 & 7) * 2;
    const int rdaddr0 = c * 128 + ((q ^ swz) << 4);          // units 8q..8q+7
    const int rdaddr1 = c * 128 + (((4 + q) ^ swz) << 4);    // units 32+8q..+7
    // hf32: LANE-LINEAR private slots: wave's b128 = 1024 contiguous B,
    // conflict-free (each lane only touches its own 16B slot).
    const int f32addr = (w * 64 + l) * 16;

    // ---- x stream base pointers (lane's seq = c) ----
    const size_t row = (size_t)(bid * 16 + c) * TT;
    const unsigned short* px = xext + row * 40;
    const float* po = obs + row * DOBS;
    const float* pa = act + row * DACT;

    const short8 zero8 = {0, 0, 0, 0, 0, 0, 0, 0};
    const f32x4 zf = {0.f, 0.f, 0.f, 0.f};

    // ---- init: zero h buffers; prime per-set x/gi state ----
    ((uint2*)hbuf)[tid] = make_uint2(0u, 0u);          // 512 x 8B = 4KB
    ((f32x4*)hf32)[tid] = zf;                          // 512 x 16B = 8KB
    short8 xo, xa;
    f32x4 cgr = zf, cgz = zf, cgn = zf;
    if (set == 0) {
        LOADX(xo, xa, 0)                    // x(0)
        cgr = MFMA(AX[0][1], xa, MFMA(AX[0][0], xo, zf));   // gi(0)
        cgz = MFMA(AX[1][1], xa, MFMA(AX[1][0], xo, zf));
        cgn = MFMA(AX[2][1], xa, MFMA(AX[2][0], xo, zf));
        LOADX(xo, xa, 2)                    // x(2) -> ring
    } else {
        LOADX(xo, xa, 1)                    // x(1) -> ring (gi(1) built in light)
    }
    f32x4 hold = zf;
    asm volatile("s_waitcnt lgkmcnt(0)" ::: "memory");
    __builtin_amdgcn_s_barrier();
    asm volatile("" ::: "memory");

    float* rew = out + (size_t)BB * HH;      // out: [h_final B*H][rewards B*T]

#pragma unroll 1
    for (int it = 0; it < TT / 2; ++it) {
        const int Ta = 2 * it, Tb = 2 * it + 1;
        // half 1: A heavy (step Ta) @prio1; B light (gi Tb + reward(Ta-1))
        if (set == 0) { HEAVY(0, Ta) } else { LIGHT(Tb, 0, Ta, it) }
        __builtin_amdgcn_s_barrier();
        asm volatile("" ::: "memory");
        // half 2: B heavy (step Tb) @prio1; A light (gi Ta+2 + reward(Tb-1))
        if (set == 1) { HEAVY(1, Tb) } else { LIGHT(Ta + 2, 1, Tb, it) }
        __builtin_amdgcn_s_barrier();
        asm volatile("" ::: "memory");
    }

    // ---- epilogue: h(T-1) is in hbuf[0]/hold of set B (T-1 = 1023 odd) ----
    if (set == 1) {
        if (w == 3) {
            short8 Ah0 = *(const short8*)((const char*)hbuf[0] + rdaddr0);
            short8 Ah1 = *(const short8*)((const char*)hbuf[0] + rdaddr1);
            f32x4 Crw = MFMA(AR[0], Ah0, zf);
            Crw = MFMA(AR[1], Ah1, Crw);
            if (q == 0)
                rew[(size_t)(bid * 16 + c) * TT + TT - 1] = Crw[0] + brr;
        }
        *(float4*)(out + (size_t)(bid * 16 + c) * HH + u0) =
            make_float4(hold[0], hold[1], hold[2], hold[3]);
    }
}

// ------------------------------------------------------------------- host ---
extern "C" void kernel_launch(void* const* d_in, const int* in_sizes, int n_in,
                              void* d_out, int out_size, void* d_ws, size_t ws_size,
                              hipStream_t stream)
{
    const float* obs    = (const float*)d_in[0];
    const float* action = (const float*)d_in[1];
    const float* W_ih   = (const float*)d_in[2];
    const float* b_ih   = (const float*)d_in[3];
    const float* W_hh   = (const float*)d_in[4];
    const float* b_hh   = (const float*)d_in[5];
    const float* W_r    = (const float*)d_in[6];
    const float* b_r    = (const float*)d_in[7];
    float* out          = (float*)d_out;

    // xext (80 MB) + slack rows so the unclamped t+4 prefetch stays in ws.
    const size_t xext_bytes = ((size_t)BB * TT + 8) * 40 * sizeof(unsigned short);
    if (ws_size >= xext_bytes) {
        unsigned short* xext = (unsigned short*)d_ws;
        pack_x<<<dim3((BB * TT) / 256), dim3(256), 0, stream>>>(obs, action, xext);
        gru_fused<true><<<dim3(BB / 16), dim3(512), 0, stream>>>(
            xext, obs, action, W_ih, b_ih, W_hh, b_hh, W_r, b_r, out);
    } else {
        gru_fused<false><<<dim3(BB / 16), dim3(512), 0, stream>>>(
            nullptr, obs, action, W_ih, b_ih, W_hh, b_hh, W_r, b_r, out);
    }
}